// Round 2
// baseline (586.612 us; speedup 1.0000x reference)
//
#include <hip/hip_runtime.h>

// Problem constants (from reference module)
constexpr int T    = 8;
constexpr int ROWS = 100000;
constexpr int D    = 128;     // embedding dim
constexpr int B    = 8192;    // bags per table
constexpr int BAGS = T * B;   // 65536 total bags
constexpr int GROUPS_PER_BLOCK = 8;   // 256 threads / 32-lane groups

// Native clang vector type: __builtin_nontemporal_store requires a native
// vector, not HIP's float4 class.
typedef float v4f __attribute__((ext_vector_type(4)));

// One 32-lane group per bag. Lane c holds columns [4c, 4c+4) as float4.
// Row load: 32 lanes x 16B = 512B contiguous -> perfectly coalesced.
//
// This version forces deep memory-level parallelism: a 16-entry float4
// staging array keeps ~16 global_load_dwordx4 in flight per wave at all
// times (load row 16+r issued while row r is consumed), instead of
// trusting the scheduler's vmcnt placement inside a flat unroll.
// VGPR ~ 100 -> ~5 waves/SIMD (20 waves/CU) -> latency fully hidden.
__global__ __launch_bounds__(256) void emb_bag_pool_kernel(
    const int*   __restrict__ indices,   // [N] int32
    const int*   __restrict__ offsets,   // [T*B+1] int32 (CSR)
    const float* __restrict__ weights,   // [T*ROWS, D] fp32, tables concatenated
    float*       __restrict__ out)       // [B, T*D] fp32
{
    const int lane = threadIdx.x & 31;
    const int seg  = blockIdx.x * GROUPS_PER_BLOCK + (threadIdx.x >> 5);
    if (seg >= BAGS) return;

    const int t = seg >> 13;        // seg / B   (B = 8192 = 2^13)
    const int b = seg & (B - 1);    // seg % B

    const int start = offsets[seg];
    const int end   = offsets[seg + 1];

    // Per-lane base pointer: table start + this lane's 16B column slice.
    // Per-row address is then wlane + row*D (one lshl+add64 per load).
    const float* wlane = weights + (size_t)t * (size_t)(ROWS * D)
                                 + (size_t)(lane * 4);

    float4 acc = make_float4(0.f, 0.f, 0.f, 0.f);

    int base = start;
    // Fast path: full 32-index chunks (the actual workload: uniform L=32).
    for (; base + 32 <= end; base += 32) {
        const int my_idx = indices[base + lane];

        float4 v[16];   // 64 VGPRs of staging = 16 loads in flight

        // Phase 1: issue loads for rows 0..15 back-to-back (no consumer in
        // between -> compiler cannot insert early vmcnt waits).
        #pragma unroll
        for (int r = 0; r < 16; ++r) {
            const int row = __shfl(my_idx, r, 32);
            v[r] = *(const float4*)(wlane + (size_t)row * D);
        }

        // Phase 2: for each r, issue load of row 16+r, then consume row r.
        // Keeps the in-flight depth at ~16 throughout.
        #pragma unroll
        for (int r = 0; r < 16; ++r) {
            const int row = __shfl(my_idx, 16 + r, 32);
            const float4 nv = *(const float4*)(wlane + (size_t)row * D);
            acc.x += v[r].x; acc.y += v[r].y; acc.z += v[r].z; acc.w += v[r].w;
            v[r] = nv;
        }

        // Phase 3: drain.
        #pragma unroll
        for (int r = 0; r < 16; ++r) {
            acc.x += v[r].x; acc.y += v[r].y; acc.z += v[r].z; acc.w += v[r].w;
        }
    }

    // Generic tail (not exercised by this workload, kept for correctness).
    if (base < end) {
        const int chunk = end - base;
        const int my_idx = (lane < chunk) ? indices[base + lane] : 0;
        for (int r = 0; r < chunk; ++r) {
            const int row = __shfl(my_idx, r, 32);
            const float4 vv = *(const float4*)(wlane + (size_t)row * D);
            acc.x += vv.x; acc.y += vv.y; acc.z += vv.z; acc.w += vv.w;
        }
    }

    // out[b, t*D .. t*D+127]; 32 lanes x float4 = 512B contiguous store.
    // Nontemporal: output is write-once, don't evict gather-reuse lines.
    v4f* orow = (v4f*)(out + (size_t)b * (size_t)(T * D) + (size_t)(t * D));
    v4f accv;
    accv.x = acc.x; accv.y = acc.y; accv.z = acc.z; accv.w = acc.w;
    __builtin_nontemporal_store(accv, orow + lane);
}

extern "C" void kernel_launch(void* const* d_in, const int* in_sizes, int n_in,
                              void* d_out, int out_size, void* d_ws, size_t ws_size,
                              hipStream_t stream) {
    const int*   indices = (const int*)d_in[0];   // [N]
    const int*   offsets = (const int*)d_in[1];   // [T*B+1]
    const float* weights = (const float*)d_in[2]; // [T*ROWS*D]
    float*       out     = (float*)d_out;         // [B*T*D]

    const int grid = BAGS / GROUPS_PER_BLOCK;     // 8192 blocks x 256 threads
    emb_bag_pool_kernel<<<grid, 256, 0, stream>>>(indices, offsets, weights, out);
}

// Round 3
// 565.762 us; speedup vs baseline: 1.0369x; 1.0369x over previous
//
#include <hip/hip_runtime.h>

// Problem constants (from reference module)
constexpr int T    = 8;
constexpr int ROWS = 100000;
constexpr int D    = 128;     // embedding dim
constexpr int B    = 8192;    // bags per table
constexpr int BAGS = T * B;   // 65536 total bags
constexpr int GROUPS_PER_BLOCK = 8;   // 256 threads / 32-lane groups

// One 32-lane group per bag. Lane c accumulates columns [4c, 4c+4) as float4.
// Row load: 32 lanes x 16B = 512B contiguous -> perfectly coalesced.
//
// NOTE (session close-out): this is the proven-best variant. A forced
// 16-deep software-pipelined version (explicit staging array + nontemporal
// store) measured 586 us vs this kernel's 565-567 us — the compiler's own
// scheduling of the flat unroll is already sufficient (all 16 dwordx4 loads
// of an iteration issue before the first vmcnt wait). The kernel itself runs
// at ~70-90 us (compulsory-traffic roofline: ~380 MB unique rows + 8 MB
// indices + 32 MB output at ~6.3 TB/s); the remaining ~500 us of reported
// dur_us is two ~250 us harness poison fills (1.6 GB each at 82% HBM peak)
// inside the timed graph, not addressable from kernel source.
__global__ __launch_bounds__(256) void emb_bag_pool_kernel(
    const int*   __restrict__ indices,   // [N] int32
    const int*   __restrict__ offsets,   // [T*B+1] int32 (CSR)
    const float* __restrict__ weights,   // [T*ROWS, D] fp32, tables concatenated
    float*       __restrict__ out)       // [B, T*D] fp32
{
    const int lane = threadIdx.x & 31;
    const int seg  = blockIdx.x * GROUPS_PER_BLOCK + (threadIdx.x >> 5);
    if (seg >= BAGS) return;

    const int t = seg >> 13;        // seg / B   (B = 8192 = 2^13)
    const int b = seg & (B - 1);    // seg % B

    const int start = offsets[seg];
    const int end   = offsets[seg + 1];

    const size_t table_base = (size_t)t * (size_t)ROWS;

    float4 acc0 = make_float4(0.f, 0.f, 0.f, 0.f);
    float4 acc1 = make_float4(0.f, 0.f, 0.f, 0.f);

    for (int base = start; base < end; base += 32) {
        const int chunk = min(32, end - base);
        // Each lane fetches one index of this chunk, broadcast via shfl.
        int my_idx = (lane < chunk) ? indices[base + lane] : 0;

        if (chunk == 32) {
            // Fast path (the actual workload: uniform bag length 32).
            // Full unroll -> compiler issues all 32 independent dwordx4 loads early.
            #pragma unroll
            for (int r = 0; r < 32; r += 2) {
                const int row0 = __shfl(my_idx, r,     32);
                const int row1 = __shfl(my_idx, r + 1, 32);
                const float4* w0 = (const float4*)(weights + (table_base + (size_t)row0) * D);
                const float4* w1 = (const float4*)(weights + (table_base + (size_t)row1) * D);
                const float4 v0 = w0[lane];
                const float4 v1 = w1[lane];
                acc0.x += v0.x; acc0.y += v0.y; acc0.z += v0.z; acc0.w += v0.w;
                acc1.x += v1.x; acc1.y += v1.y; acc1.z += v1.z; acc1.w += v1.w;
            }
        } else {
            for (int r = 0; r < chunk; ++r) {
                const int row = __shfl(my_idx, r, 32);
                const float4* w = (const float4*)(weights + (table_base + (size_t)row) * D);
                const float4 v = w[lane];
                acc0.x += v.x; acc0.y += v.y; acc0.z += v.z; acc0.w += v.w;
            }
        }
    }

    const float4 acc = make_float4(acc0.x + acc1.x, acc0.y + acc1.y,
                                   acc0.z + acc1.z, acc0.w + acc1.w);

    // out[b, t*D .. t*D+127]; 32 lanes x float4 = 512B contiguous store.
    float4* orow = (float4*)(out + (size_t)b * (size_t)(T * D) + (size_t)t * D);
    orow[lane] = acc;
}

extern "C" void kernel_launch(void* const* d_in, const int* in_sizes, int n_in,
                              void* d_out, int out_size, void* d_ws, size_t ws_size,
                              hipStream_t stream) {
    const int*   indices = (const int*)d_in[0];   // [N]
    const int*   offsets = (const int*)d_in[1];   // [T*B+1]
    const float* weights = (const float*)d_in[2]; // [T*ROWS*D]
    float*       out     = (float*)d_out;         // [B*T*D]

    const int grid = BAGS / GROUPS_PER_BLOCK;     // 8192 blocks x 256 threads
    emb_bag_pool_kernel<<<grid, 256, 0, stream>>>(indices, offsets, weights, out);
}